// Round 1
// baseline (572.591 us; speedup 1.0000x reference)
//
#include <hip/hip_runtime.h>

#define HH 6144
#define WW 6144
#define KH 11
#define KW 11
#define OH (HH - KH + 1)   // 6134
#define OW (WW - KW + 1)   // 6134

#define BT 64              // output tile edge (x and y)
#define TROWS (BT + KH - 1)   // 74 input rows staged
#define TCOLS (BT + KW - 1)   // 74 input cols needed
#define TSTR 76            // LDS row stride in dwords (16B-aligned rows, bank spread)

__global__ __launch_bounds__(256, 2)
void conv2d_11x11_kernel(const float* __restrict__ X,
                         const float* __restrict__ Wt,
                         const float* __restrict__ bias,
                         float* __restrict__ out)
{
    __shared__ float tile[TROWS][TSTR];

    const int bx = blockIdx.x, by = blockIdx.y;
    const int tid = (int)threadIdx.x;
    const int x0 = bx * BT;
    const int y0 = by * BT;

    // ---------------- stage input tile (clamped, vectorized) ----------------
    // 19 chunks of 4 dwords cover 76 dwords per row; 13 rows per pass (247 threads active)
    if (tid < 247) {
        const int c4 = tid % 19;
        const int r0 = tid / 19;           // 0..12
        const int gx = x0 + c4 * 4;
        #pragma unroll
        for (int rr = r0; rr < TROWS; rr += 13) {
            const int gy = y0 + rr;
            float4 v;
            if (gy < HH && gx + 3 < WW) {
                v = *reinterpret_cast<const float4*>(&X[(size_t)gy * WW + gx]);
            } else {
                v.x = (gy < HH && gx + 0 < WW) ? X[(size_t)gy * WW + gx + 0] : 0.f;
                v.y = (gy < HH && gx + 1 < WW) ? X[(size_t)gy * WW + gx + 1] : 0.f;
                v.z = (gy < HH && gx + 2 < WW) ? X[(size_t)gy * WW + gx + 2] : 0.f;
                v.w = (gy < HH && gx + 3 < WW) ? X[(size_t)gy * WW + gx + 3] : 0.f;
            }
            *reinterpret_cast<float4*>(&tile[rr][c4 * 4]) = v;
        }
    }

    // ---------------- weights -> registers (uniform, constant-indexed) ------
    float Wr[KH * KW];
    #pragma unroll
    for (int t = 0; t < KH * KW; ++t) Wr[t] = Wt[t];
    const float bv = bias[0];

    __syncthreads();

    // ---------------- compute 4x4 outputs per thread -------------------------
    const int tx = tid & 15;
    const int ty = tid >> 4;
    const int lx = tx * 4;     // LDS col base for this thread's outputs
    const int ly = ty * 4;     // LDS row base (== output row base within tile)

    float acc[4][4];
    #pragma unroll
    for (int r = 0; r < 4; ++r)
        #pragma unroll
        for (int c = 0; c < 4; ++c) acc[r][c] = 0.f;

    #pragma unroll
    for (int di = 0; di < KH + 3; ++di) {        // 14 input rows feed 4 output rows
        float xs[16];
        #pragma unroll
        for (int k = 0; k < 4; ++k) {
            float4 v = *reinterpret_cast<const float4*>(&tile[ly + di][lx + 4 * k]);
            xs[4 * k + 0] = v.x; xs[4 * k + 1] = v.y;
            xs[4 * k + 2] = v.z; xs[4 * k + 3] = v.w;
        }
        #pragma unroll
        for (int r = 0; r < 4; ++r) {
            // valid iff 0 <= di - r <= 10  (constant-folded after unroll)
            if (di - r < 0 || di - r > KH - 1) continue;
            const int ki = di - r;
            #pragma unroll
            for (int dj = 0; dj < KW; ++dj) {
                const float w = Wr[ki * KW + dj];
                #pragma unroll
                for (int c = 0; c < 4; ++c)
                    acc[r][c] += xs[dj + c] * w;
            }
        }
    }

    // ---------------- store (float2 pairs, 8B-aligned; guarded at edges) ----
    const int ox0 = x0 + lx;
    const int oy0 = y0 + ly;
    #pragma unroll
    for (int r = 0; r < 4; ++r) {
        const int oy = oy0 + r;
        if (oy >= OH) break;
        const size_t base = (size_t)oy * OW + ox0;
        if (ox0 + 3 < OW) {
            float2 a, b;
            a.x = acc[r][0] + bv; a.y = acc[r][1] + bv;
            b.x = acc[r][2] + bv; b.y = acc[r][3] + bv;
            *reinterpret_cast<float2*>(&out[base + 0]) = a;
            *reinterpret_cast<float2*>(&out[base + 2]) = b;
        } else {
            #pragma unroll
            for (int c = 0; c < 4; ++c)
                if (ox0 + c < OW) out[base + c] = acc[r][c] + bv;
        }
    }
}

extern "C" void kernel_launch(void* const* d_in, const int* in_sizes, int n_in,
                              void* d_out, int out_size, void* d_ws, size_t ws_size,
                              hipStream_t stream) {
    const float* X    = (const float*)d_in[0];
    const float* Wt   = (const float*)d_in[1];
    const float* bias = (const float*)d_in[2];
    float* out        = (float*)d_out;

    dim3 grid((OW + BT - 1) / BT, (OH + BT - 1) / BT);  // 96 x 96
    conv2d_11x11_kernel<<<grid, dim3(256), 0, stream>>>(X, Wt, bias, out);
}